// Round 1
// 904.994 us; speedup vs baseline: 1.0059x; 1.0059x over previous
//
#include <hip/hip_runtime.h>

typedef float v2f __attribute__((ext_vector_type(2)));

#define B_   32
#define DE_  256
#define T_   32
#define C_   128
#define HW_  16384

#define LSTRIDE 257   // 257 % 32 == 1 -> bank = (c + row) % 32, every phase <= 2-way

__device__ inline v2f vfma2(v2f a, v2f b, v2f c) {
#if __has_builtin(__builtin_elementwise_fma)
    return __builtin_elementwise_fma(a, b, c);
#else
    v2f r; r.x = fmaf(a.x, b.x, c.x); r.y = fmaf(a.y, b.y, c.y); return r;
#endif
}

// Kernel 1: e_[b][c][t] = sum_d e[b][d][t] * Wd[d][c] + bias[c]   (fp32 -> ws)
// grid (8, 32): blockIdx.x = 16-channel slab, blockIdx.y = batch. 256 threads.
__global__ __launch_bounds__(256) void dense_e_kernel(
    const float* __restrict__ e, const float* __restrict__ Wd,
    const float* __restrict__ bias, float* __restrict__ ews)
{
    __shared__ float elds[DE_ * T_];   // 32 KB, [d][t]
    __shared__ float wlds[DE_ * 16];   // 16 KB, [d][c_local]
    const int b   = blockIdx.y;
    const int cq  = blockIdx.x;        // channels [cq*16, cq*16+16)
    const int tid = threadIdx.x;       // owns d-row = tid

    {
        const float4* erow = (const float4*)(e + ((size_t)b * DE_ + tid) * T_);
        float4* edst = (float4*)(elds + tid * T_);
        #pragma unroll
        for (int i = 0; i < 8; ++i) edst[i] = erow[i];

        const float4* wrow = (const float4*)(Wd + (size_t)tid * C_ + cq * 16);
        float4* wdst = (float4*)(wlds + tid * 16);
        #pragma unroll
        for (int i = 0; i < 4; ++i) wdst[i] = wrow[i];
    }
    __syncthreads();

    const int t  = tid & 31;
    const int c8 = tid >> 5;           // 0..7
    float a0 = 0.f, a1 = 0.f;
    #pragma unroll 8
    for (int d = 0; d < DE_; ++d) {
        float ev = elds[d * T_ + t];
        a0 = fmaf(ev, wlds[d * 16 + c8],     a0);
        a1 = fmaf(ev, wlds[d * 16 + 8 + c8], a1);
    }
    const int c0 = cq * 16 + c8;
    a0 += bias[c0];
    a1 += bias[c0 + 8];
    ews[((size_t)b * C_ + c0)     * T_ + t] = a0;
    ews[((size_t)b * C_ + c0 + 8) * T_ + t] = a1;
}

// Kernel 2: fused scores + softmax(T) + context + concat copy.
// One block = 256 threads = 256 consecutive spatial positions of one batch.
// All global traffic is wave-contiguous; h is transposed through LDS in
// 32-channel chunks so the per-position compute reads LDS conflict-free.
__global__ __launch_bounds__(256) void attn_fused_kernel(
    const float* __restrict__ h,
    const float* __restrict__ ews,
    float* __restrict__ out)
{
    __shared__ float lds[32 * LSTRIDE];                   // 32.9 KB, [c_local][row]
    const int b   = blockIdx.x >> 6;                      // uniform per block
    const int n0  = (blockIdx.x & 63) << 8;               // 256-position tile
    const int tid = threadIdx.x;
    const float* __restrict__ eb = ews + (size_t)b * (C_ * T_);        // [c][t], uniform
    const float* __restrict__ hb = h   + ((size_t)b * HW_ + n0) * C_;
    float* __restrict__       ob = out + ((size_t)b * HW_ + n0) * (2 * C_);

    v2f s2[16];
    #pragma unroll
    for (int i = 0; i < 16; ++i) s2[i] = (v2f){0.f, 0.f};

    // ---- Pass 1: logits s[t] = sum_c e_[c][t] * h[n][c], chunked over c ----
    for (int cb = 0; cb < 4; ++cb) {
        // Stage: coalesced load of 256 rows x 32 ch (8 x 128B segments per
        // wave instr), direct coalesced write of the concat-copy half, and
        // transposed scatter into LDS [c_local][row].
        float4 hv[8];
        #pragma unroll
        for (int i = 0; i < 8; ++i) {
            const int idx = i * 256 + tid;
            hv[i] = *(const float4*)(hb + (size_t)(idx >> 3) * C_ + cb * 32 + (idx & 7) * 4);
        }
        #pragma unroll
        for (int i = 0; i < 8; ++i) {
            const int idx = i * 256 + tid;
            const int row = idx >> 3, c4 = idx & 7;
            *(float4*)(ob + (size_t)row * (2 * C_) + C_ + cb * 32 + c4 * 4) = hv[i];
            float* dst = lds + (c4 * 4) * LSTRIDE + row;
            dst[0]           = hv[i].x;
            dst[LSTRIDE]     = hv[i].y;
            dst[2 * LSTRIDE] = hv[i].z;
            dst[3 * LSTRIDE] = hv[i].w;
        }
        __syncthreads();

        // Compute: lanes read consecutive rows -> conflict-free b32 reads;
        // e_ rows are block-uniform -> scalar loads (SGPR operand FMAs).
        const float* ec = eb + (cb * 32) * T_;
        #pragma unroll
        for (int c = 0; c < 32; ++c) {
            const float hc = lds[c * LSTRIDE + tid];
            const v2f* er = (const v2f*)(ec + c * T_);   // uniform
            const v2f hbv = {hc, hc};
            #pragma unroll
            for (int tp = 0; tp < 16; ++tp) s2[tp] = vfma2(hbv, er[tp], s2[tp]);
        }
        __syncthreads();
    }

    // ---- Softmax over 32 logits — entirely thread-local ----
    v2f m2 = s2[0];
    #pragma unroll
    for (int i = 1; i < 16; ++i) {
        m2.x = fmaxf(m2.x, s2[i].x);
        m2.y = fmaxf(m2.y, s2[i].y);
    }
    const float m = fmaxf(m2.x, m2.y);
    float l = 0.f;
    #pragma unroll
    for (int i = 0; i < 16; ++i) {
        v2f p;
        p.x = __expf(s2[i].x - m);
        p.y = __expf(s2[i].y - m);
        s2[i] = p;
        l += p.x + p.y;
    }
    const float inv = 1.0f / l;
    #pragma unroll
    for (int i = 0; i < 16; ++i) { s2[i].x *= inv; s2[i].y *= inv; }

    // ---- Pass 2: context c_out[c] = sum_t e_[c][t] * beta[t], chunked; ----
    // stage through LDS so the global store is wave-contiguous.
    for (int cb = 0; cb < 4; ++cb) {
        #pragma unroll
        for (int c = 0; c < 32; ++c) {
            const v2f* er = (const v2f*)(eb + (size_t)(cb * 32 + c) * T_);  // uniform
            v2f a = {0.f, 0.f};
            #pragma unroll
            for (int tp = 0; tp < 16; ++tp) a = vfma2(er[tp], s2[tp], a);
            lds[c * LSTRIDE + tid] = a.x + a.y;          // lanes consecutive -> free
        }
        __syncthreads();
        #pragma unroll
        for (int i = 0; i < 8; ++i) {
            const int idx = i * 256 + tid;
            const int row = idx >> 3, c4 = idx & 7;
            const float* src = lds + (c4 * 4) * LSTRIDE + row;
            float4 st = { src[0], src[LSTRIDE], src[2 * LSTRIDE], src[3 * LSTRIDE] };
            *(float4*)(ob + (size_t)row * (2 * C_) + cb * 32 + c4 * 4) = st;
        }
        __syncthreads();
    }
}

extern "C" void kernel_launch(void* const* d_in, const int* in_sizes, int n_in,
                              void* d_out, int out_size, void* d_ws, size_t ws_size,
                              hipStream_t stream) {
    const float* e    = (const float*)d_in[0];   // [B, DE, T]
    const float* h    = (const float*)d_in[1];   // [B, H, W, C]
    const float* Wd   = (const float*)d_in[2];   // [DE, C]
    const float* bias = (const float*)d_in[3];   // [C]
    float* ews = (float*)d_ws;                   // [B, C, T] fp32 (512 KB scratch)
    float* out = (float*)d_out;                  // [B, H, W, 2C] fp32

    dense_e_kernel<<<dim3(8, 32), 256, 0, stream>>>(e, Wd, bias, ews);
    attn_fused_kernel<<<dim3(32 * (HW_ / 256)), 256, 0, stream>>>(h, ews, out);
}

// Round 3
// 866.141 us; speedup vs baseline: 1.0511x; 1.0449x over previous
//
#include <hip/hip_runtime.h>

typedef float v2f __attribute__((ext_vector_type(2)));

#define B_   32
#define DE_  256
#define T_   32
#define C_   128
#define HW_  16384

#define HSTRIDE 257   // [c_local][row] LDS stride: 257 % 32 == 1 -> conflict-free lane-consecutive reads

__device__ inline v2f vfma2(v2f a, v2f b, v2f c) {
#if __has_builtin(__builtin_elementwise_fma)
    return __builtin_elementwise_fma(a, b, c);
#else
    v2f r; r.x = fmaf(a.x, b.x, c.x); r.y = fmaf(a.y, b.y, c.y); return r;
#endif
}

// Kernel 1: e_[b][c][t] = sum_d e[b][d][t] * Wd[d][c] + bias[c]   (fp32 -> ws)
// grid (8, 32): blockIdx.x = 16-channel slab, blockIdx.y = batch. 256 threads.
__global__ __launch_bounds__(256) void dense_e_kernel(
    const float* __restrict__ e, const float* __restrict__ Wd,
    const float* __restrict__ bias, float* __restrict__ ews)
{
    __shared__ float elds[DE_ * T_];   // 32 KB, [d][t]
    __shared__ float wlds[DE_ * 16];   // 16 KB, [d][c_local]
    const int b   = blockIdx.y;
    const int cq  = blockIdx.x;        // channels [cq*16, cq*16+16)
    const int tid = threadIdx.x;       // owns d-row = tid

    {
        const float4* erow = (const float4*)(e + ((size_t)b * DE_ + tid) * T_);
        float4* edst = (float4*)(elds + tid * T_);
        #pragma unroll
        for (int i = 0; i < 8; ++i) edst[i] = erow[i];

        const float4* wrow = (const float4*)(Wd + (size_t)tid * C_ + cq * 16);
        float4* wdst = (float4*)(wlds + tid * 16);
        #pragma unroll
        for (int i = 0; i < 4; ++i) wdst[i] = wrow[i];
    }
    __syncthreads();

    const int t  = tid & 31;
    const int c8 = tid >> 5;           // 0..7
    float a0 = 0.f, a1 = 0.f;
    #pragma unroll 8
    for (int d = 0; d < DE_; ++d) {
        float ev = elds[d * T_ + t];
        a0 = fmaf(ev, wlds[d * 16 + c8],     a0);
        a1 = fmaf(ev, wlds[d * 16 + 8 + c8], a1);
    }
    const int c0 = cq * 16 + c8;
    a0 += bias[c0];
    a1 += bias[c0 + 8];
    ews[((size_t)b * C_ + c0)     * T_ + t] = a0;
    ews[((size_t)b * C_ + c0 + 8) * T_ + t] = a1;
}

// Kernel 2: fused scores + softmax(T) + context + concat copy.
// 128 threads, 256-row tile, R=2 rows per thread (rows tid and tid+128).
// e_ slice staged in LDS and read as uniform ds_read_b128 broadcasts:
// load:FMA instruction ratio 1:4 instead of the old 1:1 global-uniform loads.
__global__ __launch_bounds__(128) void attn_fused_kernel(
    const float* __restrict__ h,
    const float* __restrict__ ews,
    float* __restrict__ out)
{
    __shared__ float hT[16 * HSTRIDE];   // 16.4 KB: transposed h chunk [c_local][row]
    __shared__ float es[16 * T_];        // 2 KB: e_ slice [c_local][t]

    const int b   = blockIdx.x >> 6;                  // 32 batches
    const int n0  = (blockIdx.x & 63) << 8;           // 64 tiles x 256 rows
    const int tid = threadIdx.x;                      // 0..127
    const float* __restrict__ eb = ews + (size_t)b * (C_ * T_);
    const float* __restrict__ hb = h   + ((size_t)b * HW_ + n0) * C_;
    float* __restrict__       ob = out + ((size_t)b * HW_ + n0) * (2 * C_);

    v2f s0[16], s1[16];
    #pragma unroll
    for (int i = 0; i < 16; ++i) { s0[i] = (v2f){0.f, 0.f}; s1[i] = (v2f){0.f, 0.f}; }

    // ---- Pass 1: logits, 8 chunks of 16 channels ----
    for (int ch = 0; ch < 8; ++ch) {
        // Stage: coalesced h load (16 rows x 64B per wave instr), concat-copy
        // write, transpose-scatter into hT, and e_ slice into es.
        float4 hv[8];
        #pragma unroll
        for (int i = 0; i < 8; ++i) {
            const int idx = i * 128 + tid;
            hv[i] = *(const float4*)(hb + (size_t)(idx >> 2) * C_ + ch * 16 + (idx & 3) * 4);
        }
        ((float4*)es)[tid] = ((const float4*)(eb + ch * 16 * T_))[tid];
        #pragma unroll
        for (int i = 0; i < 8; ++i) {
            const int idx = i * 128 + tid;
            const int row = idx >> 2, c4 = idx & 3;
            *(float4*)(ob + (size_t)row * (2 * C_) + C_ + ch * 16 + c4 * 4) = hv[i];
            float* d = hT + (c4 * 4) * HSTRIDE + row;
            d[0]           = hv[i].x;
            d[HSTRIDE]     = hv[i].y;
            d[2 * HSTRIDE] = hv[i].z;
            d[3 * HSTRIDE] = hv[i].w;
        }
        __syncthreads();

        // Compute: h reads lane-consecutive (conflict-free); e reads are
        // uniform b128 broadcasts from LDS; 32 pk-FMAs per channel.
        #pragma unroll
        for (int cl = 0; cl < 16; ++cl) {
            const float h0 = hT[cl * HSTRIDE + tid];
            const float h1 = hT[cl * HSTRIDE + 128 + tid];
            const float4* ec4 = (const float4*)(es + cl * T_);
            const v2f h0v = {h0, h0}, h1v = {h1, h1};
            #pragma unroll
            for (int k = 0; k < 8; ++k) {
                const float4 ef = ec4[k];
                const v2f eA = {ef.x, ef.y}, eB = {ef.z, ef.w};
                s0[2 * k]     = vfma2(h0v, eA, s0[2 * k]);
                s0[2 * k + 1] = vfma2(h0v, eB, s0[2 * k + 1]);
                s1[2 * k]     = vfma2(h1v, eA, s1[2 * k]);
                s1[2 * k + 1] = vfma2(h1v, eB, s1[2 * k + 1]);
            }
        }
        __syncthreads();
    }

    // ---- Softmax over 32 logits, both rows, thread-local ----
    {
        v2f m2 = s0[0];
        #pragma unroll
        for (int i = 1; i < 16; ++i) { m2.x = fmaxf(m2.x, s0[i].x); m2.y = fmaxf(m2.y, s0[i].y); }
        const float m = fmaxf(m2.x, m2.y);
        float l = 0.f;
        #pragma unroll
        for (int i = 0; i < 16; ++i) {
            v2f p; p.x = __expf(s0[i].x - m); p.y = __expf(s0[i].y - m);
            s0[i] = p; l += p.x + p.y;
        }
        const float inv = 1.0f / l;
        #pragma unroll
        for (int i = 0; i < 16; ++i) { s0[i].x *= inv; s0[i].y *= inv; }
    }
    {
        v2f m2 = s1[0];
        #pragma unroll
        for (int i = 1; i < 16; ++i) { m2.x = fmaxf(m2.x, s1[i].x); m2.y = fmaxf(m2.y, s1[i].y); }
        const float m = fmaxf(m2.x, m2.y);
        float l = 0.f;
        #pragma unroll
        for (int i = 0; i < 16; ++i) {
            v2f p; p.x = __expf(s1[i].x - m); p.y = __expf(s1[i].y - m);
            s1[i] = p; l += p.x + p.y;
        }
        const float inv = 1.0f / l;
        #pragma unroll
        for (int i = 0; i < 16; ++i) { s1[i].x *= inv; s1[i].y *= inv; }
    }

    // ---- Pass 2: context, 8 chunks of 16 channels, staged out through hT ----
    for (int ch = 0; ch < 8; ++ch) {
        ((float4*)es)[tid] = ((const float4*)(eb + ch * 16 * T_))[tid];
        __syncthreads();
        #pragma unroll
        for (int cl = 0; cl < 16; ++cl) {
            const float4* ec4 = (const float4*)(es + cl * T_);
            v2f a0 = {0.f, 0.f}, a1 = {0.f, 0.f};
            #pragma unroll
            for (int k = 0; k < 8; ++k) {
                const float4 ef = ec4[k];
                const v2f eA = {ef.x, ef.y}, eB = {ef.z, ef.w};
                a0 = vfma2(eA, s0[2 * k], a0);
                a0 = vfma2(eB, s0[2 * k + 1], a0);
                a1 = vfma2(eA, s1[2 * k], a1);
                a1 = vfma2(eB, s1[2 * k + 1], a1);
            }
            hT[cl * HSTRIDE + tid]       = a0.x + a0.y;
            hT[cl * HSTRIDE + 128 + tid] = a1.x + a1.y;
        }
        __syncthreads();
        #pragma unroll
        for (int i = 0; i < 8; ++i) {
            const int idx = i * 128 + tid;
            const int row = idx >> 2, c4 = idx & 3;
            const float* src = hT + (c4 * 4) * HSTRIDE + row;
            float4 st = { src[0], src[HSTRIDE], src[2 * HSTRIDE], src[3 * HSTRIDE] };
            *(float4*)(ob + (size_t)row * (2 * C_) + ch * 16 + c4 * 4) = st;
        }
        __syncthreads();
    }
}

extern "C" void kernel_launch(void* const* d_in, const int* in_sizes, int n_in,
                              void* d_out, int out_size, void* d_ws, size_t ws_size,
                              hipStream_t stream) {
    const float* e    = (const float*)d_in[0];   // [B, DE, T]
    const float* h    = (const float*)d_in[1];   // [B, H, W, C]
    const float* Wd   = (const float*)d_in[2];   // [DE, C]
    const float* bias = (const float*)d_in[3];   // [C]
    float* ews = (float*)d_ws;                   // [B, C, T] fp32 (512 KB scratch)
    float* out = (float*)d_out;                  // [B, H, W, 2C] fp32

    dense_e_kernel<<<dim3(8, 32), 256, 0, stream>>>(e, Wd, bias, ews);
    attn_fused_kernel<<<dim3(32 * (HW_ / 256)), 128, 0, stream>>>(h, ews, out);
}

// Round 4
// 835.966 us; speedup vs baseline: 1.0890x; 1.0361x over previous
//
#include <hip/hip_runtime.h>

typedef float v2f __attribute__((ext_vector_type(2)));

#define B_   32
#define DE_  256
#define T_   32
#define C_   128
#define HW_  16384

#define HSTRIDE 257   // [c_local][row] LDS stride: 257 % 32 == 1 -> conflict-free lane-consecutive reads

__device__ inline v2f vfma2(v2f a, v2f b, v2f c) {
#if __has_builtin(__builtin_elementwise_fma)
    return __builtin_elementwise_fma(a, b, c);
#else
    v2f r; r.x = fmaf(a.x, b.x, c.x); r.y = fmaf(a.y, b.y, c.y); return r;
#endif
}

// Kernel 1: e_[b][c][t] = sum_d e[b][d][t] * Wd[d][c] + bias[c]   (fp32 -> ws)
// grid (8, 32): blockIdx.x = 16-channel slab, blockIdx.y = batch. 256 threads.
__global__ __launch_bounds__(256) void dense_e_kernel(
    const float* __restrict__ e, const float* __restrict__ Wd,
    const float* __restrict__ bias, float* __restrict__ ews)
{
    __shared__ float elds[DE_ * T_];   // 32 KB, [d][t]
    __shared__ float wlds[DE_ * 16];   // 16 KB, [d][c_local]
    const int b   = blockIdx.y;
    const int cq  = blockIdx.x;        // channels [cq*16, cq*16+16)
    const int tid = threadIdx.x;       // owns d-row = tid

    {
        const float4* erow = (const float4*)(e + ((size_t)b * DE_ + tid) * T_);
        float4* edst = (float4*)(elds + tid * T_);
        #pragma unroll
        for (int i = 0; i < 8; ++i) edst[i] = erow[i];

        const float4* wrow = (const float4*)(Wd + (size_t)tid * C_ + cq * 16);
        float4* wdst = (float4*)(wlds + tid * 16);
        #pragma unroll
        for (int i = 0; i < 4; ++i) wdst[i] = wrow[i];
    }
    __syncthreads();

    const int t  = tid & 31;
    const int c8 = tid >> 5;           // 0..7
    float a0 = 0.f, a1 = 0.f;
    #pragma unroll 8
    for (int d = 0; d < DE_; ++d) {
        float ev = elds[d * T_ + t];
        a0 = fmaf(ev, wlds[d * 16 + c8],     a0);
        a1 = fmaf(ev, wlds[d * 16 + 8 + c8], a1);
    }
    const int c0 = cq * 16 + c8;
    a0 += bias[c0];
    a1 += bias[c0 + 8];
    ews[((size_t)b * C_ + c0)     * T_ + t] = a0;
    ews[((size_t)b * C_ + c0 + 8) * T_ + t] = a1;
}

// Kernel 2: fused scores + softmax(T) + context + concat copy.
// 128 threads, 256-row tile, R=2 rows per thread (rows tid and tid+128).
// Register double-buffering: chunk ch+1's h tile and e_ slice are loaded
// into registers DURING compute of chunk ch, so the per-chunk barrier no
// longer exposes HBM latency on the critical path.
__global__ __launch_bounds__(128) void attn_fused_kernel(
    const float* __restrict__ h,
    const float* __restrict__ ews,
    float* __restrict__ out)
{
    __shared__ float hT[16 * HSTRIDE];   // 16.45 KB: transposed h chunk [c_local][row]
    __shared__ float es[2][16 * T_];     // 2 x 2 KB: double-buffered e_ slice [c_local][t]

    const int b   = blockIdx.x >> 6;                  // 32 batches
    const int n0  = (blockIdx.x & 63) << 8;           // 64 tiles x 256 rows
    const int tid = threadIdx.x;                      // 0..127
    const float* __restrict__ eb = ews + (size_t)b * (C_ * T_);
    const float* __restrict__ hb = h   + ((size_t)b * HW_ + n0) * C_;
    float* __restrict__       ob = out + ((size_t)b * HW_ + n0) * (2 * C_);

    v2f s0[16], s1[16];
    #pragma unroll
    for (int i = 0; i < 16; ++i) { s0[i] = (v2f){0.f, 0.f}; s1[i] = (v2f){0.f, 0.f}; }

    // ---- Pass 1: logits, 8 chunks of 16 channels, reg-double-buffered ----
    float4 hv[8];
    #pragma unroll
    for (int i = 0; i < 8; ++i) {
        const int idx = i * 128 + tid;
        hv[i] = *(const float4*)(hb + (size_t)(idx >> 2) * C_ + (idx & 3) * 4);
    }
    float4 ereg = ((const float4*)(eb))[tid];

    for (int ch = 0; ch < 8; ++ch) {
        if (ch) __syncthreads();          // hT free (previous compute done)

        // Scatter prefetched h into hT; stash e_ slice.
        #pragma unroll
        for (int i = 0; i < 8; ++i) {
            const int idx = i * 128 + tid;
            const int row = idx >> 2, c4 = idx & 3;
            float* d = hT + (c4 * 4) * HSTRIDE + row;
            d[0]           = hv[i].x;
            d[HSTRIDE]     = hv[i].y;
            d[2 * HSTRIDE] = hv[i].z;
            d[3 * HSTRIDE] = hv[i].w;
        }
        ((float4*)es[ch & 1])[tid] = ereg;
        __syncthreads();                  // hT + es ready

        // Concat-copy store (after barrier: its vmcnt drain lands next iter,
        // covered by a full compute phase).
        #pragma unroll
        for (int i = 0; i < 8; ++i) {
            const int idx = i * 128 + tid;
            const int row = idx >> 2, c4 = idx & 3;
            *(float4*)(ob + (size_t)row * (2 * C_) + C_ + ch * 16 + c4 * 4) = hv[i];
        }
        // Prefetch next chunk into registers (latency hidden under compute).
        if (ch < 7) {
            #pragma unroll
            for (int i = 0; i < 8; ++i) {
                const int idx = i * 128 + tid;
                hv[i] = *(const float4*)(hb + (size_t)(idx >> 2) * C_ + (ch + 1) * 16 + (idx & 3) * 4);
            }
            ereg = ((const float4*)(eb + (ch + 1) * 16 * T_))[tid];
        }

        // Compute: h reads lane-consecutive (conflict-free); e reads are
        // uniform b128 broadcasts from LDS; 32 pk-FMAs per channel.
        const float* esc = es[ch & 1];
        #pragma unroll
        for (int cl = 0; cl < 16; ++cl) {
            const float h0 = hT[cl * HSTRIDE + tid];
            const float h1 = hT[cl * HSTRIDE + 128 + tid];
            const float4* ec4 = (const float4*)(esc + cl * T_);
            const v2f h0v = {h0, h0}, h1v = {h1, h1};
            #pragma unroll
            for (int k = 0; k < 8; ++k) {
                const float4 ef = ec4[k];
                const v2f eA = {ef.x, ef.y}, eB = {ef.z, ef.w};
                s0[2 * k]     = vfma2(h0v, eA, s0[2 * k]);
                s0[2 * k + 1] = vfma2(h0v, eB, s0[2 * k + 1]);
                s1[2 * k]     = vfma2(h1v, eA, s1[2 * k]);
                s1[2 * k + 1] = vfma2(h1v, eB, s1[2 * k + 1]);
            }
        }
    }

    // ---- Softmax over 32 logits, both rows, thread-local ----
    {
        v2f m2 = s0[0];
        #pragma unroll
        for (int i = 1; i < 16; ++i) { m2.x = fmaxf(m2.x, s0[i].x); m2.y = fmaxf(m2.y, s0[i].y); }
        const float m = fmaxf(m2.x, m2.y);
        float l = 0.f;
        #pragma unroll
        for (int i = 0; i < 16; ++i) {
            v2f p; p.x = __expf(s0[i].x - m); p.y = __expf(s0[i].y - m);
            s0[i] = p; l += p.x + p.y;
        }
        const float inv = 1.0f / l;
        #pragma unroll
        for (int i = 0; i < 16; ++i) { s0[i].x *= inv; s0[i].y *= inv; }
    }
    {
        v2f m2 = s1[0];
        #pragma unroll
        for (int i = 1; i < 16; ++i) { m2.x = fmaxf(m2.x, s1[i].x); m2.y = fmaxf(m2.y, s1[i].y); }
        const float m = fmaxf(m2.x, m2.y);
        float l = 0.f;
        #pragma unroll
        for (int i = 0; i < 16; ++i) {
            v2f p; p.x = __expf(s1[i].x - m); p.y = __expf(s1[i].y - m);
            s1[i] = p; l += p.x + p.y;
        }
        const float inv = 1.0f / l;
        #pragma unroll
        for (int i = 0; i < 16; ++i) { s1[i].x *= inv; s1[i].y *= inv; }
    }

    // ---- Pass 2: context, 8 chunks; es double-buffered, reg-prefetched ----
    float4 ep0 = ((const float4*)(eb))[tid];
    float4 ep1 = ((const float4*)(eb + 16 * T_))[tid];
    __syncthreads();                      // hT + es free (pass-1 readers done)
    ((float4*)es[0])[tid] = ep0;
    ((float4*)es[1])[tid] = ep1;
    __syncthreads();                      // es[0], es[1] ready
    float4 epn = ((const float4*)(eb + 2 * 16 * T_))[tid];   // chunk 2 in flight

    for (int ch = 0; ch < 8; ++ch) {
        const float* esc = es[ch & 1];
        #pragma unroll
        for (int cl = 0; cl < 16; ++cl) {
            const float4* ec4 = (const float4*)(esc + cl * T_);
            v2f a0 = {0.f, 0.f}, a1 = {0.f, 0.f};
            #pragma unroll
            for (int k = 0; k < 8; ++k) {
                const float4 ef = ec4[k];
                const v2f eA = {ef.x, ef.y}, eB = {ef.z, ef.w};
                a0 = vfma2(eA, s0[2 * k], a0);
                a0 = vfma2(eB, s0[2 * k + 1], a0);
                a1 = vfma2(eA, s1[2 * k], a1);
                a1 = vfma2(eB, s1[2 * k + 1], a1);
            }
            hT[cl * HSTRIDE + tid]       = a0.x + a0.y;
            hT[cl * HSTRIDE + 128 + tid] = a1.x + a1.y;
        }
        __syncthreads();                  // hT ready; all threads done reading es[ch&1]
        if (ch < 6) ((float4*)es[ch & 1])[tid] = epn;                    // stage chunk ch+2
        if (ch < 5) epn = ((const float4*)(eb + (ch + 3) * 16 * T_))[tid];
        #pragma unroll
        for (int i = 0; i < 8; ++i) {
            const int idx = i * 128 + tid;
            const int row = idx >> 2, c4 = idx & 3;
            const float* src = hT + (c4 * 4) * HSTRIDE + row;
            float4 st = { src[0], src[HSTRIDE], src[2 * HSTRIDE], src[3 * HSTRIDE] };
            *(float4*)(ob + (size_t)row * (2 * C_) + ch * 16 + c4 * 4) = st;
        }
        if (ch < 7) __syncthreads();      // hT free for next chunk's writes
    }
}

extern "C" void kernel_launch(void* const* d_in, const int* in_sizes, int n_in,
                              void* d_out, int out_size, void* d_ws, size_t ws_size,
                              hipStream_t stream) {
    const float* e    = (const float*)d_in[0];   // [B, DE, T]
    const float* h    = (const float*)d_in[1];   // [B, H, W, C]
    const float* Wd   = (const float*)d_in[2];   // [DE, C]
    const float* bias = (const float*)d_in[3];   // [C]
    float* ews = (float*)d_ws;                   // [B, C, T] fp32 (512 KB scratch)
    float* out = (float*)d_out;                  // [B, H, W, 2C] fp32

    dense_e_kernel<<<dim3(8, 32), 256, 0, stream>>>(e, Wd, bias, ews);
    attn_fused_kernel<<<dim3(32 * (HW_ / 256)), 128, 0, stream>>>(h, ews, out);
}